// Round 1
// 112.659 us; speedup vs baseline: 1.0797x; 1.0797x over previous
//
#include <hip/hip_runtime.h>

#define B_ 16
#define N_ 1024
#define F_ 16
#define E_ 12
#define H_ 4

// workspace layout (float offsets)
#define OFF_QS 0         // 393216: self Q planes (RAW, uncentered) [unit128][3][1024]
#define OFF_QC 393216    // 196608: cross Q planes [unit64][3][1024]
#define OFF_PS 589824    // 45056: self raw moments + x-sums, per chunk [side*16+b][chunk8][176]
#define OFF_PC 634880    // 20480: cross moments, per chunk [b][chunk8][160]

// moment layout per unit (39 used):
// [0:3]=Sum k | [3:9]=Sum kk (00,11,22,01,02,12) | [9:12]=Sum v
// [12:21]=Sum k_i v_c | [21:39]=Sum kk_pair v_c
// partS cols: [h*40 + j] for j<39, plus [160:176] = Sum x (16 features)

__device__ __forceinline__ void mom_compute(float k0, float k1, float k2,
                                            float v0, float v1, float v2, float* m) {
  m[0]=k0; m[1]=k1; m[2]=k2;
  float s00=k0*k0, s11=k1*k1, s22=k2*k2, s01=k0*k1, s02=k0*k2, s12=k1*k2;
  m[3]=s00; m[4]=s11; m[5]=s22; m[6]=s01; m[7]=s02; m[8]=s12;
  m[9]=v0; m[10]=v1; m[11]=v2;
  m[12]=k0*v0; m[13]=k0*v1; m[14]=k0*v2;
  m[15]=k1*v0; m[16]=k1*v1; m[17]=k1*v2;
  m[18]=k2*v0; m[19]=k2*v1; m[20]=k2*v2;
  m[21]=s00*v0; m[22]=s00*v1; m[23]=s00*v2;
  m[24]=s11*v0; m[25]=s11*v1; m[26]=s11*v2;
  m[27]=s22*v0; m[28]=s22*v1; m[29]=s22*v2;
  m[30]=s01*v0; m[31]=s01*v1; m[32]=s01*v2;
  m[33]=s02*v0; m[34]=s02*v1; m[35]=s02*v2;
  m[36]=s12*v0; m[37]=s12*v1; m[38]=s12*v2;
}

// eval with pre-scaled moments (diag 2nd-order entries x0.5 applied at smu stage)
__device__ __forceinline__ void attn_eval(const float* __restrict__ mu,
                                          float p0, float p1, float p2, float* out) {
  float pp0=p0*p0, pp1=p1*p1, pp2=p2*p2;
  float q01=p0*p1, q02=p0*p2, q12=p1*p2;
  float den = (float)N_;
  den = fmaf(p0, mu[0], den); den = fmaf(p1, mu[1], den); den = fmaf(p2, mu[2], den);
  den = fmaf(pp0, mu[3], den); den = fmaf(pp1, mu[4], den); den = fmaf(pp2, mu[5], den);
  den = fmaf(q01, mu[6], den); den = fmaf(q02, mu[7], den); den = fmaf(q12, mu[8], den);
  float inv = 1.0f / den;
#pragma unroll
  for (int c = 0; c < 3; c++) {
    float num = mu[9+c];
    num = fmaf(p0, mu[12+c], num); num = fmaf(p1, mu[15+c], num); num = fmaf(p2, mu[18+c], num);
    num = fmaf(pp0, mu[21+c], num); num = fmaf(pp1, mu[24+c], num); num = fmaf(pp2, mu[27+c], num);
    num = fmaf(q01, mu[30+c], num); num = fmaf(q02, mu[33+c], num); num = fmaf(q12, mu[36+c], num);
    out[c] = num * inv;
  }
}

__device__ __forceinline__ float mom_scale(int j) {
  return ((j >= 3 && j < 6) || (j >= 21 && j < 30)) ? 0.5f : 1.0f;
}

// ---------------- K1: raw W_in + QKV_self -> Q planes + raw self moments + x-sums ---------
// No centering here: mean is folded into K2 via shifted-moment identities.
// Per-chunk partial outputs (plain stores) -> no atomics, no zero-init kernel.
__global__ __launch_bounds__(128, 1)
void k_proj(const float* __restrict__ xo, const float* __restrict__ yo,
            const float* __restrict__ W_in, const float* __restrict__ b_in,
            const float* __restrict__ Wqkv, const float* __restrict__ bqkv,
            float* __restrict__ Qs, float* __restrict__ partS) {
  __shared__ float sw[672];          // W_in 192 | b_in 12 | Wqkv_s 432 | bqkv_s 36
  __shared__ float red[32 * 180];    // [quad32][4*40 moments + 16 xsum, stride 180]
  int tid = threadIdx.x;
  int blk = blockIdx.x;
  int side = blk >> 7;
  int rem  = blk & 127;
  int b = rem >> 3, c = rem & 7;
  for (int i = tid; i < 672; i += 128) {
    float v;
    if (i < 192) v = W_in[i];
    else if (i < 204) v = b_in[i - 192];
    else if (i < 636) v = Wqkv[i - 204];
    else v = bqkv[i - 636];
    sw[i] = v;
  }
  __syncthreads();
  int n = c * 128 + tid;
  int t = b * N_ + n;
  const float* in = (side ? yo : xo) + (size_t)t * F_;
  float xv[F_];
  {
    const float4* p = (const float4*)in;
#pragma unroll
    for (int q = 0; q < 4; q++) {
      float4 v = p[q];
      xv[4*q+0]=v.x; xv[4*q+1]=v.y; xv[4*q+2]=v.z; xv[4*q+3]=v.w;
    }
  }
  float xi[E_];                       // raw (uncentered) xi' = x@W_in^T + b_in
#pragma unroll
  for (int e = 0; e < E_; e++) {
    float s = sw[192 + e];
#pragma unroll
    for (int f = 0; f < F_; f++) s = fmaf(xv[f], sw[e*F_+f], s);
    xi[e] = s;
  }
  int ub = (side ? 64 : 0) + b * 4;
  int qd = tid >> 2;
  bool rep = (tid & 3) == 0;
#pragma unroll
  for (int h = 0; h < H_; h++) {
    float qkv[9];
#pragma unroll
    for (int d = 0; d < 9; d++) {
      int o = (d/3)*12 + h*3 + (d%3);   // q=h*3+c, k=12+h*3+c, v=24+h*3+c
      float s = sw[636 + o];
#pragma unroll
      for (int e = 0; e < E_; e++) s = fmaf(xi[e], sw[204 + o*E_ + e], s);
      qkv[d] = s;
    }
#pragma unroll
    for (int d = 0; d < 3; d++) Qs[(ub + h)*3072 + d*1024 + n] = qkv[d];
    float m[40];
    mom_compute(qkv[3], qkv[4], qkv[5], qkv[6], qkv[7], qkv[8], m);
    m[39] = 0.f;
#pragma unroll
    for (int j = 0; j < 39; j++) {
      m[j] += __shfl_xor(m[j], 1);
      m[j] += __shfl_xor(m[j], 2);
    }
    if (rep) {
#pragma unroll
      for (int j4 = 0; j4 < 10; j4++)
        *(float4*)&red[qd*180 + h*40 + j4*4] =
          make_float4(m[j4*4], m[j4*4+1], m[j4*4+2], m[j4*4+3]);
    }
  }
  {
    float s[F_];
#pragma unroll
    for (int f = 0; f < F_; f++) {
      float v = xv[f];
      v += __shfl_xor(v, 1);
      v += __shfl_xor(v, 2);
      s[f] = v;
    }
    if (rep) {
#pragma unroll
      for (int j4 = 0; j4 < 4; j4++)
        *(float4*)&red[qd*180 + 160 + j4*4] =
          make_float4(s[j4*4], s[j4*4+1], s[j4*4+2], s[j4*4+3]);
    }
  }
  __syncthreads();
  for (int col = tid; col < 176; col += 128) {
    float a = 0.f;
#pragma unroll
    for (int qq = 0; qq < 32; qq++) a += red[qq*180 + col];
    partS[((size_t)(side*16 + b)*8 + c)*176 + col] = a;
  }
}

// ---- K2: shift-correct moments, self-eval + Wo_s + QKV_cross; x->Qc, y->cross moments ----
__global__ __launch_bounds__(128, 1)
void k_mid(const float* __restrict__ Qs, const float* __restrict__ partS,
           const float* __restrict__ Wo_s, const float* __restrict__ bo_s,
           const float* __restrict__ Wqkv_c, const float* __restrict__ bqkv_c,
           const float* __restrict__ W_in, const float* __restrict__ Wqkv_s,
           float* __restrict__ Qc, float* __restrict__ partC) {
  __shared__ float sw[1248];   // Wo_s 0 | bo_s 144 | Wqkv_c 156 | bqkv_c 588 | W_in 624 | Wqkv_s 816
  __shared__ float smu[160];   // corrected + pre-scaled moments
  __shared__ float dq[12];     // q-shift per head
  __shared__ float rawR[176];  // raw sums for this (side,b)
  __shared__ float red[32 * 164];
  int tid = threadIdx.x;
  int blk = blockIdx.x;
  int side = blk >> 7;
  int rem  = blk & 127;
  int b = rem >> 3, c = rem & 7;
  int ub = (side ? 64 : 0) + b * 4;
  for (int i = tid; i < 1248; i += 128) {
    float v;
    if (i < 144) v = Wo_s[i];
    else if (i < 156) v = bo_s[i-144];
    else if (i < 588) v = Wqkv_c[i-156];
    else if (i < 624) v = bqkv_c[i-588];
    else if (i < 816) v = W_in[i-624];
    else v = Wqkv_s[i-816];
    sw[i] = v;
  }
  for (int col = tid; col < 176; col += 128) {
    float a = 0.f;
#pragma unroll
    for (int cc = 0; cc < 8; cc++)
      a += partS[((size_t)(side*16 + b)*8 + cc)*176 + col];
    rawR[col] = a;
  }
  __syncthreads();
  // ---- per-head shifted-moment correction (threads 0..3) ----
  if (tid < H_) {
    int h = tid;
    const float invN = 1.0f / N_;
    const float Nf = (float)N_;
    float del[E_];               // delta = mu @ W_in^T   (no bias)
#pragma unroll
    for (int e = 0; e < E_; e++) {
      float s = 0.f;
#pragma unroll
      for (int f = 0; f < F_; f++) s = fmaf(rawR[160+f], sw[624 + e*F_ + f], s);
      del[e] = s * invN;
    }
    float A[3], G[3];            // k-shift, v-shift for this head
#pragma unroll
    for (int d = 0; d < 3; d++) {
      float sq=0.f, sk=0.f, sv=0.f;
#pragma unroll
      for (int e = 0; e < E_; e++) {
        sq = fmaf(del[e], sw[816 + (h*3+d)*E_ + e], sq);
        sk = fmaf(del[e], sw[816 + (12 + h*3+d)*E_ + e], sk);
        sv = fmaf(del[e], sw[816 + (24 + h*3+d)*E_ + e], sv);
      }
      dq[h*3+d] = sq; A[d] = sk; G[d] = sv;
    }
    const float* R = &rawR[h*40];
    float S[39];
#pragma unroll
    for (int i = 0; i < 3; i++) S[i] = R[i] - Nf*A[i];
    const int PI[6] = {0,1,2,0,0,1}, PJ[6] = {0,1,2,1,2,2};
#pragma unroll
    for (int p = 0; p < 6; p++) {
      int i = PI[p], j = PJ[p];
      S[3+p] = R[3+p] - A[i]*R[j] - A[j]*R[i] + Nf*A[i]*A[j];
    }
#pragma unroll
    for (int cc = 0; cc < 3; cc++) S[9+cc] = R[9+cc] - Nf*G[cc];
#pragma unroll
    for (int i = 0; i < 3; i++)
#pragma unroll
      for (int cc = 0; cc < 3; cc++)
        S[12+i*3+cc] = R[12+i*3+cc] - A[i]*R[9+cc] - G[cc]*R[i] + Nf*A[i]*G[cc];
#pragma unroll
    for (int p = 0; p < 6; p++) {
      int i = PI[p], j = PJ[p];
#pragma unroll
      for (int cc = 0; cc < 3; cc++) {
        S[21+p*3+cc] = R[21+p*3+cc]
                     - A[i]*R[12+j*3+cc] - A[j]*R[12+i*3+cc]
                     - G[cc]*R[3+p]
                     + A[i]*A[j]*R[9+cc]
                     + A[i]*G[cc]*R[j] + A[j]*G[cc]*R[i]
                     - Nf*A[i]*A[j]*G[cc];
      }
    }
#pragma unroll
    for (int j = 0; j < 39; j++) smu[h*40+j] = S[j] * mom_scale(j);
    smu[h*40+39] = 0.f;
  }
  __syncthreads();
  int n = c * 128 + tid;
  const float SC = 0.57735026918962584f;   // 1/sqrt(3)
  float attn[E_];
#pragma unroll
  for (int h = 0; h < H_; h++) {
    float p0 = (Qs[(ub+h)*3072 + n]        - dq[h*3+0]) * SC;
    float p1 = (Qs[(ub+h)*3072 + 1024 + n] - dq[h*3+1]) * SC;
    float p2 = (Qs[(ub+h)*3072 + 2048 + n] - dq[h*3+2]) * SC;
    attn_eval(&smu[h*40], p0, p1, p2, &attn[h*3]);
  }
  float i2[E_];
#pragma unroll
  for (int e = 0; e < E_; e++) {
    float s = sw[144+e];
#pragma unroll
    for (int j = 0; j < E_; j++) s = fmaf(attn[j], sw[e*E_+j], s);
    i2[e] = s;
  }
  if (!side) {                        // x side -> Q_c planes
#pragma unroll
    for (int h = 0; h < H_; h++)
#pragma unroll
      for (int d = 0; d < 3; d++) {
        int o = h*3 + d;
        float s = sw[588+o];
#pragma unroll
        for (int e = 0; e < E_; e++) s = fmaf(i2[e], sw[156 + o*E_ + e], s);
        Qc[(b*4+h)*3072 + d*1024 + n] = s;
      }
  } else {                            // y side -> cross moments (already centered: no fixup)
    int qd = tid >> 2;
    bool rep = (tid & 3) == 0;
#pragma unroll
    for (int h = 0; h < H_; h++) {
      float kv[6];
#pragma unroll
      for (int d = 0; d < 6; d++) {
        int o = 12 + (d/3)*12 + h*3 + (d%3);
        float s = sw[588+o];
#pragma unroll
        for (int e = 0; e < E_; e++) s = fmaf(i2[e], sw[156 + o*E_ + e], s);
        kv[d] = s;
      }
      float m[40];
      mom_compute(kv[0], kv[1], kv[2], kv[3], kv[4], kv[5], m);
      m[39] = 0.f;
#pragma unroll
      for (int j = 0; j < 39; j++) {
        m[j] += __shfl_xor(m[j], 1);
        m[j] += __shfl_xor(m[j], 2);
      }
      if (rep) {
#pragma unroll
        for (int j4 = 0; j4 < 10; j4++)
          *(float4*)&red[qd*164 + h*40 + j4*4] =
            make_float4(m[j4*4], m[j4*4+1], m[j4*4+2], m[j4*4+3]);
      }
    }
    __syncthreads();                  // block-uniform branch (side per block)
    for (int col = tid; col < 160; col += 128) {
      float a = 0.f;
#pragma unroll
      for (int qq = 0; qq < 32; qq++) a += red[qq*164 + col];
      partC[((size_t)b*8 + c)*160 + col] = a;
    }
  }
}

// ---- K3: cross-eval + Wo_c + W_out + in-block Kabsch stats + polar + transform ----
// 16 blocks x 256 threads; block owns batch b; 4 tokens/thread.
__global__ __launch_bounds__(256, 1)
void k_fin(const float* __restrict__ Qc, const float* __restrict__ partC,
           const float* __restrict__ partS, const float* __restrict__ xo,
           const float* __restrict__ Wo_c, const float* __restrict__ bo_c,
           const float* __restrict__ W_out, const float* __restrict__ b_out,
           float* __restrict__ out) {
  __shared__ float sw[195];          // Wo_c 144 | bo_c 12 | W_out 36 | b_out 3
  __shared__ float smu[160];
  __shared__ float sred[4][16];
  __shared__ float sstats[16];
  __shared__ float mxy[6];           // mu_x[0:3], mu_y[0:3]
  int tid = threadIdx.x;
  int b = blockIdx.x;
  for (int i = tid; i < 195; i += 256) {
    float v;
    if (i < 144) v = Wo_c[i];
    else if (i < 156) v = bo_c[i-144];
    else if (i < 192) v = W_out[i-156];
    else v = b_out[i-192];
    sw[i] = v;
  }
  if (tid < 160) {
    float a = 0.f;
#pragma unroll
    for (int cc = 0; cc < 8; cc++) a += partC[((size_t)b*8 + cc)*160 + tid];
    int h = tid / 40, j = tid - h*40;
    smu[tid] = a * mom_scale(j);
  } else if (tid < 166) {
    int k = tid - 160;                // k = side*3 + comp
    int side = k / 3, comp = k - side*3;
    float a = 0.f;
#pragma unroll
    for (int cc = 0; cc < 8; cc++)
      a += partS[((size_t)(side*16 + b)*8 + cc)*176 + 160 + comp];
    mxy[k] = a * (1.0f / N_);
  }
  __syncthreads();
  const float SC = 0.57735026918962584f;
  float st[15];
#pragma unroll
  for (int i = 0; i < 15; i++) st[i] = 0.f;
  float x3r[4][3];
#pragma unroll
  for (int r = 0; r < 4; r++) {
    int n = r*256 + tid;
    int t = b * N_ + n;
    float attn[E_];
#pragma unroll
    for (int h = 0; h < H_; h++) {
      float p0 = Qc[(b*4+h)*3072 + n] * SC;
      float p1 = Qc[(b*4+h)*3072 + 1024 + n] * SC;
      float p2 = Qc[(b*4+h)*3072 + 2048 + n] * SC;
      attn_eval(&smu[h*40], p0, p1, p2, &attn[h*3]);
    }
    float c12[E_];
#pragma unroll
    for (int e = 0; e < E_; e++) {
      float s = sw[144+e];
#pragma unroll
      for (int j = 0; j < E_; j++) s = fmaf(attn[j], sw[e*E_+j], s);
      c12[e] = s;
    }
    float co[3];
#pragma unroll
    for (int k = 0; k < 3; k++) {
      float s = sw[192+k];
#pragma unroll
      for (int e = 0; e < E_; e++) s = fmaf(c12[e], sw[156 + k*E_ + e], s);
      co[k] = s;
    }
    float4 xl = *(const float4*)(xo + (size_t)t * F_);
    float x0 = xl.x - mxy[0], x1 = xl.y - mxy[1], x2 = xl.z - mxy[2];
    x3r[r][0]=x0; x3r[r][1]=x1; x3r[r][2]=x2;
    float A0 = co[0]+x0, A1 = co[1]+x1, A2 = co[2]+x2;
    st[0]+=co[0]; st[1]+=co[1]; st[2]+=co[2];
    st[3]+=x0; st[4]+=x1; st[5]+=x2;
    st[6]=fmaf(x0,A0,st[6]);  st[7]=fmaf(x0,A1,st[7]);  st[8]=fmaf(x0,A2,st[8]);
    st[9]=fmaf(x1,A0,st[9]);  st[10]=fmaf(x1,A1,st[10]); st[11]=fmaf(x1,A2,st[11]);
    st[12]=fmaf(x2,A0,st[12]); st[13]=fmaf(x2,A1,st[13]); st[14]=fmaf(x2,A2,st[14]);
  }
#pragma unroll
  for (int i = 0; i < 15; i++) {
    st[i] += __shfl_down(st[i], 32); st[i] += __shfl_down(st[i], 16);
    st[i] += __shfl_down(st[i], 8);  st[i] += __shfl_down(st[i], 4);
    st[i] += __shfl_down(st[i], 2);  st[i] += __shfl_down(st[i], 1);
  }
  int wv = tid >> 6;
  if ((tid & 63) == 0) {
#pragma unroll
    for (int i = 0; i < 15; i++) sred[wv][i] = st[i];
  }
  __syncthreads();
  if (tid < 15) sstats[tid] = sred[0][tid] + sred[1][tid] + sred[2][tid] + sred[3][tid];
  __syncthreads();
  // ---- redundant uniform polar per thread ----
  const float* s = sstats;
  float invN = 1.0f / N_;
  float cB[3] = { s[3]*invN, s[4]*invN, s[5]*invN };
  float cA[3] = { (s[0]+s[3])*invN, (s[1]+s[4])*invN, (s[2]+s[5])*invN };
  float X[9];
#pragma unroll
  for (int i = 0; i < 3; i++)
#pragma unroll
    for (int j = 0; j < 3; j++)
      X[i*3+j] = s[6 + i*3 + j] - (float)N_ * cB[i] * cA[j];
  float fn = 0.f;
#pragma unroll
  for (int i = 0; i < 9; i++) fn += X[i]*X[i];
  float scl = rsqrtf(fn);
#pragma unroll
  for (int i = 0; i < 9; i++) X[i] *= scl;
  for (int it = 0; it < 24; it++) {
    float c00 =  X[4]*X[8]-X[5]*X[7];
    float c01 = -(X[3]*X[8]-X[5]*X[6]);
    float c02 =  X[3]*X[7]-X[4]*X[6];
    float c10 = -(X[1]*X[8]-X[2]*X[7]);
    float c11 =  X[0]*X[8]-X[2]*X[6];
    float c12_= -(X[0]*X[7]-X[1]*X[6]);
    float c20 =  X[1]*X[5]-X[2]*X[4];
    float c21 = -(X[0]*X[5]-X[2]*X[3]);
    float c22 =  X[0]*X[4]-X[1]*X[3];
    float det = X[0]*c00 + X[1]*c01 + X[2]*c02;
    float id = 0.5f / det;
    X[0]=0.5f*X[0]+c00*id; X[1]=0.5f*X[1]+c01*id; X[2]=0.5f*X[2]+c02*id;
    X[3]=0.5f*X[3]+c10*id; X[4]=0.5f*X[4]+c11*id; X[5]=0.5f*X[5]+c12_*id;
    X[6]=0.5f*X[6]+c20*id; X[7]=0.5f*X[7]+c21*id; X[8]=0.5f*X[8]+c22*id;
  }
  float tt[3];
#pragma unroll
  for (int k = 0; k < 3; k++)
    tt[k] = cA[k] - (cB[0]*X[k] + cB[1]*X[3+k] + cB[2]*X[6+k]) + mxy[3+k];
#pragma unroll
  for (int r = 0; r < 4; r++) {
    size_t t = (size_t)b * N_ + r*256 + tid;
#pragma unroll
    for (int k = 0; k < 3; k++) {
      float v = fmaf(x3r[r][0], X[k], fmaf(x3r[r][1], X[3+k], fmaf(x3r[r][2], X[6+k], tt[k])));
      out[t*3+k] = v;
    }
  }
}

extern "C" void kernel_launch(void* const* d_in, const int* in_sizes, int n_in,
                              void* d_out, int out_size, void* d_ws, size_t ws_size,
                              hipStream_t stream) {
  const float* x_orig = (const float*)d_in[0];
  const float* y_orig = (const float*)d_in[1];
  const float* W_in   = (const float*)d_in[2];
  const float* b_in   = (const float*)d_in[3];
  const float* Wqkv_s = (const float*)d_in[4];
  const float* bqkv_s = (const float*)d_in[5];
  const float* Wo_s   = (const float*)d_in[6];
  const float* bo_s   = (const float*)d_in[7];
  const float* Wqkv_c = (const float*)d_in[8];
  const float* bqkv_c = (const float*)d_in[9];
  const float* Wo_c   = (const float*)d_in[10];
  const float* bo_c   = (const float*)d_in[11];
  const float* W_out  = (const float*)d_in[12];
  const float* b_out  = (const float*)d_in[13];
  float* ws = (float*)d_ws;

  k_proj<<<256, 128, 0, stream>>>(x_orig, y_orig, W_in, b_in, Wqkv_s, bqkv_s,
                                  ws+OFF_QS, ws+OFF_PS);
  k_mid<<<256, 128, 0, stream>>>(ws+OFF_QS, ws+OFF_PS, Wo_s, bo_s, Wqkv_c, bqkv_c,
                                 W_in, Wqkv_s, ws+OFF_QC, ws+OFF_PC);
  k_fin<<<16, 256, 0, stream>>>(ws+OFF_QC, ws+OFF_PC, ws+OFF_PS, x_orig,
                                Wo_c, bo_c, W_out, b_out, (float*)d_out);
}